// Round 6
// baseline (1505.163 us; speedup 1.0000x reference)
//
#include <hip/hip_runtime.h>
#include <hip/hip_bf16.h>
#include <cmath>
#include <cstdint>

#define B_ 2
#define N_ 8192
#define H_ 12
#define D_ 64
#define E_ 768
#define M_ (B_*N_)   // 16384

typedef __attribute__((ext_vector_type(8))) short short8;
typedef __attribute__((ext_vector_type(4))) short short4v;
typedef __attribute__((ext_vector_type(4))) float float4v;

__device__ inline short f2b(float f) {
  union { float f; unsigned u; } x; x.f = f;
  unsigned r = (x.u + 0x7fffu + ((x.u >> 16) & 1u)) >> 16;
  return (short)r;
}
__device__ inline float b2f(short s) {
  union { unsigned u; float f; } x; x.u = ((unsigned)(unsigned short)s) << 16;
  return x.f;
}
// round-to-nearest hi + bf16 lo: residual ~2^-18 relative
__device__ inline void split2(float f, short& h, short& l) {
  h = f2b(f);
  l = f2b(f - b2f(h));
}
__device__ inline unsigned pack_trunc(float a, float b) {  // lo16=trunc(a), hi16=trunc(b)
  return (__float_as_uint(b) & 0xffff0000u) | (__float_as_uint(a) >> 16);
}

#define MFMA(a, b, c) __builtin_amdgcn_mfma_f32_16x16x32_bf16((a), (b), (c), 0, 0, 0)

// K=16 bf16 MFMA: B-frag layout k = quad*4+e matches the 16x16 C-layout row
// stride (quad*4+i), so softmax output feeds PV directly from registers.
#if __has_builtin(__builtin_amdgcn_mfma_f32_16x16x16_bf16)
#define MFMA16(a, b, c) __builtin_amdgcn_mfma_f32_16x16x16_bf16((a), (b), (c), 0, 0, 0)
#elif __has_builtin(__builtin_amdgcn_mfma_f32_16x16x16bf16_1k)
#define MFMA16(a, b, c) __builtin_amdgcn_mfma_f32_16x16x16bf16_1k((a), (b), (c), 0, 0, 0)
#else
__device__ inline float4v mfma16_asm(short4v a, short4v b, float4v c) {
  float4v d = c;
  asm volatile("v_mfma_f32_16x16x16_bf16 %0, %1, %2, %0"
               : "+v"(d) : "v"(a), "v"(b));
  return d;
}
#define MFMA16(a, b, c) mfma16_asm((a), (b), (c))
#endif

#define GLOAD_LDS16(g, l) \
  __builtin_amdgcn_global_load_lds((const __attribute__((address_space(1))) void*)(g), \
      (__attribute__((address_space(3))) void*)(l), 16, 0, 0)

// fp32 -> bf16 hi/lo planes
__global__ __launch_bounds__(256) void split_kernel(const float* __restrict__ src,
    short* __restrict__ hi, short* __restrict__ lo, int count4)
{
  int i = blockIdx.x * 256 + threadIdx.x;
  if (i >= count4) return;
  float4v t = ((const float4v*)src)[i];
  short4v h4, l4; short hh, ll;
  split2(t.x, hh, ll); h4.x = hh; l4.x = ll;
  split2(t.y, hh, ll); h4.y = hh; l4.y = ll;
  split2(t.z, hh, ll); h4.z = hh; l4.z = ll;
  split2(t.w, hh, ll); h4.w = hh; l4.w = ll;
  ((short4v*)hi)[i] = h4;
  ((short4v*)lo)[i] = l4;
}

// all 4 weight matrices in one launch (blockIdx.y selects)
__global__ __launch_bounds__(256) void split_w4(
    const float* __restrict__ w0, const float* __restrict__ w1,
    const float* __restrict__ w2, const float* __restrict__ w3,
    short* __restrict__ planes)   // 8 planes of E*E shorts: h0,l0,h1,l1,...
{
  int which = blockIdx.y;
  const float* src = which == 0 ? w0 : which == 1 ? w1 : which == 2 ? w2 : w3;
  short* hi = planes + (size_t)(2 * which) * (E_ * E_);
  short* lo = planes + (size_t)(2 * which + 1) * (E_ * E_);
  int i = blockIdx.x * 256 + threadIdx.x;
  if (i >= E_ * E_ / 4) return;
  float4v t = ((const float4v*)src)[i];
  short4v h4, l4; short hh, ll;
  split2(t.x, hh, ll); h4.x = hh; l4.x = ll;
  split2(t.y, hh, ll); h4.y = hh; l4.y = ll;
  split2(t.z, hh, ll); h4.z = hh; l4.z = ll;
  split2(t.w, hh, ll); h4.w = hh; l4.w = ll;
  ((short4v*)hi)[i] = h4;
  ((short4v*)lo)[i] = l4;
}

__global__ __launch_bounds__(256) void inv_kernel(const float* __restrict__ sums,
    float* __restrict__ inv)
{
  int i = blockIdx.x * 256 + threadIdx.x;
  if (i < B_ * E_) inv[i] = 1.0f / sums[i];
}

// xnorm = attn[b,n,e] * inv[b,e] -> bf16 hi/lo planes
__global__ __launch_bounds__(256) void prep_out(const float* __restrict__ attn,
    const float* __restrict__ inv, short* __restrict__ xnh, short* __restrict__ xnl)
{
  size_t e4 = ((size_t)blockIdx.x * 256 + threadIdx.x) * 4;
  int e = (int)(e4 % E_);
  int b = (int)(e4 / ((size_t)E_ * N_));
  float4v a = *(const float4v*)(attn + e4);
  float4v iv = *(const float4v*)(inv + (size_t)b * E_ + e);
  a *= iv;
  short4v h4, l4; short hh, ll;
  split2(a.x, hh, ll); h4.x = hh; l4.x = ll;
  split2(a.y, hh, ll); h4.y = hh; l4.y = ll;
  split2(a.z, hh, ll); h4.z = hh; l4.z = ll;
  split2(a.w, hh, ll); h4.w = hh; l4.w = ll;
  *(short4v*)&xnh[e4] = h4;
  *(short4v*)&xnl[e4] = l4;
}

// C[m][n] = (sum_k A[m][k]*W[n][k] + bias[n]) * oscale, 3-product split precision.
// XCD-aware block swizzle (768 = 8*96): each XCD owns 16 consecutive m-tiles
// x all 6 n-tiles -> blocks sharing an A-tile co-resident on one L2.
template<bool OUT_PAIR>
__global__ __launch_bounds__(256) void gemm_dma(
    const short* __restrict__ Ah, const short* __restrict__ Al,
    const short* __restrict__ Wh, const short* __restrict__ Wl,
    const float* __restrict__ bias, void* __restrict__ OutH, short* __restrict__ OutL,
    float oscale)
{
  __shared__ short Ash[4096], Asl[4096], Wsh[4096], Wsl[4096];  // 128 rows x 32 k each
  const int tid = threadIdx.x;
  const int flat = blockIdx.x + blockIdx.y * 6;       // grid fixed at (6,128)
  const int nid = (flat & 7) * 96 + (flat >> 3);      // bijective: 768 = 8*96
  const int m0 = (nid / 6) * 128;
  const int n0 = (nid % 6) * 128;
  const int w = tid >> 6, lane = tid & 63, quad = lane >> 4, l16 = lane & 15;
  const int wr = w >> 1, wc = w & 1;
  const int cq = (l16 >> 1) & 3;
  const int dmarow = lane >> 2;                         // + c*16
  const int dmacc = (((lane & 3) ^ ((lane >> 3) & 3))) * 8;

  float4v acc[4][4];
#pragma unroll
  for (int a = 0; a < 4; ++a)
#pragma unroll
    for (int c = 0; c < 4; ++c) acc[a][c] = (float4v)0.0f;

  for (int kt = 0; kt < 24; ++kt) {
    const int k0 = kt * 32;
#pragma unroll
    for (int i = 0; i < 2; ++i) {
      int c = w * 2 + i;
      int ldso = c * 512 + lane * 8;                    // shorts
      size_t ga = (size_t)(m0 + c * 16 + dmarow) * E_ + k0 + dmacc;
      size_t gw = (size_t)(n0 + c * 16 + dmarow) * E_ + k0 + dmacc;
      GLOAD_LDS16(Ah + ga, &Ash[ldso]);
      GLOAD_LDS16(Al + ga, &Asl[ldso]);
      GLOAD_LDS16(Wh + gw, &Wsh[ldso]);
      GLOAD_LDS16(Wl + gw, &Wsl[ldso]);
    }
    __syncthreads();

    short8 afh[4], afl[4], bfh[4], bfl[4];
#pragma unroll
    for (int rt = 0; rt < 4; ++rt) {
      int ao = (wr * 64 + rt * 16 + l16) * 32 + (quad ^ cq) * 8;
      afh[rt] = *(const short8*)&Ash[ao];
      afl[rt] = *(const short8*)&Asl[ao];
      int wo = (wc * 64 + rt * 16 + l16) * 32 + (quad ^ cq) * 8;
      bfh[rt] = *(const short8*)&Wsh[wo];
      bfl[rt] = *(const short8*)&Wsl[wo];
    }
#pragma unroll
    for (int rt = 0; rt < 4; ++rt)
#pragma unroll
      for (int ct = 0; ct < 4; ++ct) {
        float4v a = acc[rt][ct];
        a = MFMA(afh[rt], bfh[ct], a);
        a = MFMA(afh[rt], bfl[ct], a);
        a = MFMA(afl[rt], bfh[ct], a);
        acc[rt][ct] = a;
      }
    __syncthreads();
  }

#pragma unroll
  for (int ct = 0; ct < 4; ++ct) {
    int n = n0 + wc * 64 + ct * 16 + l16;
    float bv = bias[n];
#pragma unroll
    for (int rt = 0; rt < 4; ++rt) {
#pragma unroll
      for (int i = 0; i < 4; ++i) {
        int m = m0 + wr * 64 + rt * 16 + quad * 4 + i;
        float v = (acc[rt][ct][i] + bv) * oscale;
        if constexpr (OUT_PAIR) {
          short hh, ll; split2(v, hh, ll);
          ((short*)OutH)[(size_t)m * E_ + n] = hh;
          OutL[(size_t)m * E_ + n] = ll;
        } else {
          ((float*)OutH)[(size_t)m * E_ + n] = v;
        }
      }
    }
  }
}

// cumulative jj-extent offset per head: g=h>>2, ext=8192>>g
__device__ __host__ inline int hoff_of(int g, int hg) {
  return g == 0 ? hg * 8192 : (g == 1 ? 32768 + hg * 4096 : 49152 + hg * 2048);
}

// V [b][n][h][d] hi/lo -> gathered transposed Vg [b][h][d][jj]
__global__ __launch_bounds__(256) void transpose_v(const short* __restrict__ vh,
    const short* __restrict__ vl, short* __restrict__ vgh, short* __restrict__ vgl)
{
  __shared__ short Lh[64 * 68], Ll[64 * 68];
  int bid = blockIdx.x;
  int b = 0;
  if (bid >= 896) { b = 1; bid -= 896; }
  int g, hg, tile;
  if (bid < 512)      { g = 0; hg = bid >> 7; tile = bid & 127; }
  else if (bid < 768) { g = 1; hg = (bid - 512) >> 6; tile = (bid - 512) & 63; }
  else                { g = 2; hg = (bid - 768) >> 5; tile = (bid - 768) & 31; }
  const int h = g * 4 + hg, r = 1 << g, off = g;
  const int ext = 8192 >> g;
  const int jj0 = tile * 64, seg = jj0 >> 11, j0 = jj0 & 2047;
  const int n0 = seg * (2048 << g) + off + j0 * r;
  const int tid = threadIdx.x;

#pragma unroll
  for (int p = 0; p < 2; ++p) {
    int c = tid + p * 256;
    int jr = c >> 3, c8 = (c & 7) * 8;
    size_t gsrc = ((size_t)(b * N_ + n0 + jr * r) * H_ + h) * D_ + c8;
    *(short8*)&Lh[jr * 68 + c8] = *(const short8*)(vh + gsrc);
    *(short8*)&Ll[jr * 68 + c8] = *(const short8*)(vl + gsrc);
  }
  __syncthreads();
  size_t basebh = ((size_t)b * 57344 + hoff_of(g, hg)) * 64;
#pragma unroll
  for (int p = 0; p < 2; ++p) {
    int c = tid + p * 256;
    int dd = c >> 3, jc = (c & 7) * 8;
    short8 oh, ol;
#pragma unroll
    for (int u = 0; u < 8; ++u) {
      oh[u] = Lh[(jc + u) * 68 + dd];
      ol[u] = Ll[(jc + u) * 68 + dd];
    }
    size_t gdst = basebh + (size_t)dd * ext + jj0 + jc;
    *(short8*)(vgh + gdst) = oh;
    *(short8*)(vgl + gdst) = ol;
  }
}

// Flash attention, S^T = K*Q^T / O^T = V^T*P^T, split precision.
// v6: QBLK 128->64 (grid 896->1792, 1 q-subtile/wave) to fix grid-limited
// occupancy (24% -> target ~60%). K direct-to-reg from global (L2-resident,
// v5). V LDS swizzle CORRECTED via quarter-wave bank model: phys 8B chunk =
// data chunk ^ (row>>1 & 7) -> 16 lanes cover all 32 banks exactly once on
// PV reads (v5's ^(l16&7) aliased l16 vs l16+8 -> 2-way). Writes: 16B granule
// XOR vc^((vd>>2)&3), half-swap when (vd>>1)&1; pre-swizzled global source.
// PV via K=16 MFMAs from registers (v4).
__global__ __launch_bounds__(256, 5) void attn_kernel(
    const short* __restrict__ qh, const short* __restrict__ ql,
    const short* __restrict__ kh, const short* __restrict__ kl,
    const short* __restrict__ vgh, const short* __restrict__ vgl,
    float* __restrict__ attn_out, float* __restrict__ sums)
{
  __shared__ __align__(16) short Vth[2][64 * 32], Vtl[2][64 * 32];

  // XCD swizzle: 1792 = 8*224; contiguous logical ids (sharing K/V) per XCD
  int bid = (blockIdx.x & 7) * 224 + (blockIdx.x >> 3);
  int g, t;
  if (bid < 1024)      { g = 0; t = bid; }
  else if (bid < 1536) { g = 1; t = bid - 1024; }
  else                 { g = 2; t = bid - 1536; }
  const int qtile = t & 31; t >>= 5;
  const int hg = t & 3; t >>= 2;
  const int nseg = 4 >> g;
  const int seg = t & (nseg - 1);
  const int b = t / nseg;
  const int r = 1 << g;
  const int off = g;
  const int h = g * 4 + hg;
  const int segbase = seg * (2048 << g);
  const int ext = 8192 >> g;

  const int tid = threadIdx.x;
  const int w = tid >> 6, lane = tid & 63, quad = lane >> 4, l16 = lane & 15;

  const size_t vbase = ((size_t)b * 57344 + hoff_of(g, hg)) * 64 + (size_t)seg * 2048;

  // zero-fill uncovered attn slots for this block's q-range (64 rows)
  if (g > 0) {
#pragma unroll
    for (int res0 = 1; res0 < 4; ++res0) {
      if (res0 >= r) break;
      int res = (off + res0) & (r - 1);
      for (int c = 0; c < 4; ++c) {
        int idx = tid + c * 256;
        int jl = idx >> 4, d0 = (idx & 15) * 4;
        int pos = segbase + res + (qtile * 64 + jl) * r;
        *(float4v*)(attn_out + ((size_t)(b * N_ + pos) * H_ + h) * D_ + d0) = (float4v)0.f;
      }
    }
  }

  // Q B-frags (n = l16 = q, k = quad*8+j [+32*ks]); Q pre-scaled by 0.125*log2e
  short8 qfh[2], qfl[2];
  {
    int j = qtile * 64 + w * 16 + l16;
    int pos = segbase + off + j * r;
    size_t base = ((size_t)(b * N_ + pos) * H_ + h) * D_;
#pragma unroll
    for (int ks = 0; ks < 2; ++ks) {
      qfh[ks] = *(const short8*)(qh + base + ks * 32 + quad * 8);
      qfl[ks] = *(const short8*)(ql + base + ks * 32 + quad * 8);
    }
  }

  // V staging geometry (corrected XOR swizzle)
  const int vd = tid >> 2;                  // row d 0..63
  const int vc = tid & 3;                   // phys 16B chunk 0..3
  const int vg16 = vc ^ ((vd >> 2) & 3);    // global 16B chunk (pre-swizzled)
  const bool vswap = ((vd >> 1) & 1) != 0;  // 8B half-swap
  const int vldso = vd * 32 + vc * 8;       // shorts (row stride 32 shorts = 64B)
  const int vm = l16 >> 1;                  // read-side 8B-chunk XOR mask
  size_t gbV = vbase + (size_t)vd * ext + vg16 * 8;

  // K direct-load geometry: lane's A-frag = K[row kvt*16+l16][quad*8 + ks*32]
  size_t kbase = ((size_t)(b * N_ + segbase + off + l16 * r) * H_ + h) * D_ + quad * 8;
  const size_t krstep = (size_t)r * (H_ * D_);

  short8 rvh, rvl;
  short8 kf_h[2][2], kf_l[2][2];   // [kvt][ks]
#define LOADV(tt) do { size_t va_ = gbV + (size_t)(tt) * 32; \
    rvh = *(const short8*)(vgh + va_); rvl = *(const short8*)(vgl + va_); } while (0)
#define WRITEV(cc) do { \
    short8 th_ = vswap ? __builtin_shufflevector(rvh, rvh, 4, 5, 6, 7, 0, 1, 2, 3) : rvh; \
    short8 tl_ = vswap ? __builtin_shufflevector(rvl, rvl, 4, 5, 6, 7, 0, 1, 2, 3) : rvl; \
    *(short8*)&Vth[cc][vldso] = th_; \
    *(short8*)&Vtl[cc][vldso] = tl_; } while (0)
#define KLOAD(tt) do { \
    size_t ka_ = kbase + (size_t)((tt) * 32) * krstep; \
    size_t kb_ = ka_ + 16 * krstep; \
    kf_h[0][0] = *(const short8*)(kh + ka_); \
    kf_h[0][1] = *(const short8*)(kh + ka_ + 32); \
    kf_l[0][0] = *(const short8*)(kl + ka_); \
    kf_l[0][1] = *(const short8*)(kl + ka_ + 32); \
    kf_h[1][0] = *(const short8*)(kh + kb_); \
    kf_h[1][1] = *(const short8*)(kh + kb_ + 32); \
    kf_l[1][0] = *(const short8*)(kl + kb_); \
    kf_l[1][1] = *(const short8*)(kl + kb_ + 32); \
  } while (0)

  float4v o[4];
  float mrow = -INFINITY, lrow = 0.f;
#pragma unroll
  for (int dt = 0; dt < 4; ++dt) o[dt] = (float4v)0.0f;

  // prologue: V0 -> buf0; V1 in regs; K0 in regs
  LOADV(0);
  WRITEV(0);
  LOADV(1);
  KLOAD(0);
  __syncthreads();
  int cur = 0;

  for (int kt = 0; kt < 64; ++kt) {
    WRITEV(cur ^ 1);          // V(kt+1) (regs arrived last iter)
    LOADV((kt + 2) & 63);     // issue V(kt+2)

    // S^T = K*Q^T (3-product split); K from registers, scale folded into Q
    float4v sc[2];
    __builtin_amdgcn_s_setprio(1);
#pragma unroll
    for (int kvt = 0; kvt < 2; ++kvt) {
      float4v a = (float4v)0.0f;
      a = MFMA(kf_h[kvt][0], qfh[0], a); a = MFMA(kf_h[kvt][1], qfh[1], a);
      a = MFMA(kf_h[kvt][0], qfl[0], a); a = MFMA(kf_h[kvt][1], qfl[1], a);
      a = MFMA(kf_l[kvt][0], qfh[0], a); a = MFMA(kf_l[kvt][1], qfh[1], a);
      sc[kvt] = a;
    }
    __builtin_amdgcn_s_setprio(0);

    KLOAD((kt + 1) & 63);     // issue K(kt+1) after QK consumed the regs

    // online softmax (exp2 domain), q = l16; P stays in registers (K=16 frags)
    short4v pfh[2], pfl[2];   // [kvt]
    {
      float mx = fmaxf(fmaxf(fmaxf(sc[0][0], sc[0][1]),
                             fmaxf(sc[0][2], sc[0][3])),
                       fmaxf(fmaxf(sc[1][0], sc[1][1]),
                             fmaxf(sc[1][2], sc[1][3])));
      mx = fmaxf(mx, __shfl_xor(mx, 16, 64));
      mx = fmaxf(mx, __shfl_xor(mx, 32, 64));
      // T13 defer-max: only rescale when the max grew by more than 8
      if (__any(mx > mrow + 8.0f)) {
        float mnew = fmaxf(mrow, mx);
        float alpha = exp2f(mrow - mnew);
        mrow = mnew;
        lrow *= alpha;
#pragma unroll
        for (int dt = 0; dt < 4; ++dt) o[dt] *= alpha;
      }
      float rs = 0.f;
#pragma unroll
      for (int kvt = 0; kvt < 2; ++kvt) {
        float p0 = exp2f(sc[kvt][0] - mrow);
        float p1 = exp2f(sc[kvt][1] - mrow);
        float p2 = exp2f(sc[kvt][2] - mrow);
        float p3 = exp2f(sc[kvt][3] - mrow);
        rs += (p0 + p1) + (p2 + p3);
        union { unsigned u[2]; short4v s; } ph, pl;
        ph.u[0] = pack_trunc(p0, p1);
        ph.u[1] = pack_trunc(p2, p3);
        float l0 = p0 - __uint_as_float(__float_as_uint(p0) & 0xffff0000u);
        float l1 = p1 - __uint_as_float(__float_as_uint(p1) & 0xffff0000u);
        float l2 = p2 - __uint_as_float(__float_as_uint(p2) & 0xffff0000u);
        float l3 = p3 - __uint_as_float(__float_as_uint(p3) & 0xffff0000u);
        pl.u[0] = pack_trunc(l0, l1);
        pl.u[1] = pack_trunc(l2, l3);
        pfh[kvt] = ph.s;
        pfl[kvt] = pl.s;
      }
      lrow += rs;   // lane-partial; reduced across quads in epilogue
    }

    // O^T += V^T * P^T  (K=16 MFMAs; V via swizzled 8B reads, P from regs)
    __builtin_amdgcn_s_setprio(1);
    {
      const short* Vc_h = Vth[cur];
      const short* Vc_l = Vtl[cur];
#pragma unroll
      for (int dt = 0; dt < 4; ++dt) {
#pragma unroll
        for (int kvt = 0; kvt < 2; ++kvt) {
          const int vo = (dt * 16 + l16) * 32 + ((kvt * 4 + quad) ^ vm) * 4;
          short4v vfh = *(const short4v*)&Vc_h[vo];
          short4v vfl = *(const short4v*)&Vc_l[vo];
          float4v a = o[dt];
          a = MFMA16(vfh, pfh[kvt], a);
          a = MFMA16(vfh, pfl[kvt], a);
          a = MFMA16(vfl, pfh[kvt], a);
          o[dt] = a;
        }
      }
    }
    __builtin_amdgcn_s_setprio(0);

    __syncthreads();
    cur ^= 1;
  }
#undef LOADV
#undef WRITEV
#undef KLOAD

  // epilogue: finish deferred l-sum reduction, then write O and column sums
  float4v sacc[4];
#pragma unroll
  for (int dt = 0; dt < 4; ++dt) sacc[dt] = (float4v)0.0f;
  {
    lrow += __shfl_xor(lrow, 16, 64);
    lrow += __shfl_xor(lrow, 32, 64);
    float inv_l = 1.0f / lrow;
    int j = qtile * 64 + w * 16 + l16;
    int pos = segbase + off + j * r;
    float* dst = attn_out + ((size_t)(b * N_ + pos) * H_ + h) * D_;
#pragma unroll
    for (int dt = 0; dt < 4; ++dt) {
      float4v v = o[dt] * inv_l;
      *(float4v*)(dst + dt * 16 + quad * 4) = v;
      sacc[dt] += v;
    }
  }
#pragma unroll
  for (int dt = 0; dt < 4; ++dt) {
#pragma unroll
    for (int i = 0; i < 4; ++i) {
      float x = sacc[dt][i];
      x += __shfl_xor(x, 1, 64);
      x += __shfl_xor(x, 2, 64);
      x += __shfl_xor(x, 4, 64);
      x += __shfl_xor(x, 8, 64);
      if (l16 == 0)
        atomicAdd(&sums[(size_t)b * E_ + h * D_ + dt * 16 + quad * 4 + i], x);
    }
  }
}

extern "C" void kernel_launch(void* const* d_in, const int* in_sizes, int n_in,
                              void* d_out, int out_size, void* d_ws, size_t ws_size,
                              hipStream_t stream)
{
  const float* query = (const float*)d_in[0];
  const float* key_  = (const float*)d_in[1];
  const float* value = (const float*)d_in[2];
  const float* Wq = (const float*)d_in[3];
  const float* bq = (const float*)d_in[4];
  const float* Wk = (const float*)d_in[5];
  const float* bk = (const float*)d_in[6];
  const float* Wv = (const float*)d_in[7];
  const float* bv = (const float*)d_in[8];
  const float* Wo = (const float*)d_in[9];
  const float* bo = (const float*)d_in[10];

  char* ws = (char*)d_ws;
  const size_t szbf = (size_t)M_ * E_ * 2;           // 25,165,824
  const size_t szvg = (size_t)2 * 57344 * 64 * 2;    // 14,680,064
  const size_t szw  = (size_t)E_ * E_ * 2;           // 1,179,648
  short* qh_ = (short*)(ws);
  short* ql_ = (short*)(ws + 1 * szbf);
  short* kh_ = (short*)(ws + 2 * szbf);
  short* kl_ = (short*)(ws + 3 * szbf);
  short* vh_ = (short*)(ws + 4 * szbf);
  short* vl_ = (short*)(ws + 5 * szbf);
  // [6szbf, 8szbf): input-split scratch (serial q,k,v), later overlaid by vg
  short* ish = (short*)(ws + 6 * szbf);
  short* isl = (short*)(ws + 7 * szbf);
  short* vgh = (short*)(ws + 6 * szbf);
  short* vgl = (short*)(ws + 6 * szbf + szvg);
  short* wsp = (short*)(ws + 8 * szbf);              // 8 weight planes
  float* sums = (float*)(ws + 8 * szbf + 8 * szw);
  float* attn = (float*)(ws + 4 * szbf);             // overlays vh/vl (dead after transpose)
  float* inv  = (float*)qh_;                         // q dead after attn_kernel
  short* xnh = kh_;                                  // k dead after attn_kernel
  short* xnl = kl_;
  short* wqh = wsp + 0 * (szw / 2), *wql = wsp + 1 * (szw / 2);
  short* wkh = wsp + 2 * (szw / 2), *wkl = wsp + 3 * (szw / 2);
  short* wvh = wsp + 4 * (szw / 2), *wvl = wsp + 5 * (szw / 2);
  short* woh = wsp + 6 * (szw / 2), *wol = wsp + 7 * (szw / 2);

  hipMemsetAsync(sums, 0, (size_t)B_ * E_ * sizeof(float), stream);

  split_w4<<<dim3(576, 4), 256, 0, stream>>>(Wq, Wk, Wv, Wo, wsp);

  const int ac4 = M_ * E_ / 4;                       // 3,145,728 -> 12288 blocks
  dim3 gg(6, 128), gb(256);
  const float qscale = 0.18033688f;                  // 0.125 * log2(e)
  split_kernel<<<12288, 256, 0, stream>>>(query, ish, isl, ac4);
  gemm_dma<true><<<gg, gb, 0, stream>>>(ish, isl, wqh, wql, bq, qh_, ql_, qscale);
  split_kernel<<<12288, 256, 0, stream>>>(key_, ish, isl, ac4);
  gemm_dma<true><<<gg, gb, 0, stream>>>(ish, isl, wkh, wkl, bk, kh_, kl_, 1.0f);
  split_kernel<<<12288, 256, 0, stream>>>(value, ish, isl, ac4);
  gemm_dma<true><<<gg, gb, 0, stream>>>(ish, isl, wvh, wvl, bv, vh_, vl_, 1.0f);

  transpose_v<<<1792, 256, 0, stream>>>(vh_, vl_, vgh, vgl);
  attn_kernel<<<1792, 256, 0, stream>>>(qh_, ql_, kh_, kl_, vgh, vgl, attn, sums);
  inv_kernel<<<6, 256, 0, stream>>>(sums, inv);
  prep_out<<<12288, 256, 0, stream>>>(attn, inv, xnh, xnl);
  gemm_dma<false><<<gg, gb, 0, stream>>>(xnh, xnl, woh, wol, bo, d_out, nullptr, 1.0f);
}

// Round 7
// 799.050 us; speedup vs baseline: 1.8837x; 1.8837x over previous
//
#include <hip/hip_runtime.h>
#include <hip/hip_bf16.h>
#include <cmath>
#include <cstdint>

#define B_ 2
#define N_ 8192
#define H_ 12
#define D_ 64
#define E_ 768
#define M_ (B_*N_)   // 16384

typedef __attribute__((ext_vector_type(8))) short short8;
typedef __attribute__((ext_vector_type(4))) short short4v;
typedef __attribute__((ext_vector_type(4))) float float4v;

__device__ inline short f2b(float f) {
  union { float f; unsigned u; } x; x.f = f;
  unsigned r = (x.u + 0x7fffu + ((x.u >> 16) & 1u)) >> 16;
  return (short)r;
}
__device__ inline float b2f(short s) {
  union { unsigned u; float f; } x; x.u = ((unsigned)(unsigned short)s) << 16;
  return x.f;
}
// round-to-nearest hi + bf16 lo: residual ~2^-18 relative
__device__ inline void split2(float f, short& h, short& l) {
  h = f2b(f);
  l = f2b(f - b2f(h));
}
__device__ inline unsigned pack_trunc(float a, float b) {  // lo16=trunc(a), hi16=trunc(b)
  return (__float_as_uint(b) & 0xffff0000u) | (__float_as_uint(a) >> 16);
}

#define MFMA(a, b, c) __builtin_amdgcn_mfma_f32_16x16x32_bf16((a), (b), (c), 0, 0, 0)

// K=16 bf16 MFMA: B-frag layout k = quad*4+e matches the 16x16 C-layout row
// stride (quad*4+i), so softmax output feeds PV directly from registers.
#if __has_builtin(__builtin_amdgcn_mfma_f32_16x16x16_bf16)
#define MFMA16(a, b, c) __builtin_amdgcn_mfma_f32_16x16x16_bf16((a), (b), (c), 0, 0, 0)
#elif __has_builtin(__builtin_amdgcn_mfma_f32_16x16x16bf16_1k)
#define MFMA16(a, b, c) __builtin_amdgcn_mfma_f32_16x16x16bf16_1k((a), (b), (c), 0, 0, 0)
#else
__device__ inline float4v mfma16_asm(short4v a, short4v b, float4v c) {
  float4v d = c;
  asm volatile("v_mfma_f32_16x16x16_bf16 %0, %1, %2, %0"
               : "+v"(d) : "v"(a), "v"(b));
  return d;
}
#define MFMA16(a, b, c) mfma16_asm((a), (b), (c))
#endif

#define GLOAD_LDS16(g, l) \
  __builtin_amdgcn_global_load_lds((const __attribute__((address_space(1))) void*)(g), \
      (__attribute__((address_space(3))) void*)(l), 16, 0, 0)

// fp32 -> bf16 hi/lo planes
__global__ __launch_bounds__(256) void split_kernel(const float* __restrict__ src,
    short* __restrict__ hi, short* __restrict__ lo, int count4)
{
  int i = blockIdx.x * 256 + threadIdx.x;
  if (i >= count4) return;
  float4v t = ((const float4v*)src)[i];
  short4v h4, l4; short hh, ll;
  split2(t.x, hh, ll); h4.x = hh; l4.x = ll;
  split2(t.y, hh, ll); h4.y = hh; l4.y = ll;
  split2(t.z, hh, ll); h4.z = hh; l4.z = ll;
  split2(t.w, hh, ll); h4.w = hh; l4.w = ll;
  ((short4v*)hi)[i] = h4;
  ((short4v*)lo)[i] = l4;
}

// all 4 weight matrices in one launch (blockIdx.y selects)
__global__ __launch_bounds__(256) void split_w4(
    const float* __restrict__ w0, const float* __restrict__ w1,
    const float* __restrict__ w2, const float* __restrict__ w3,
    short* __restrict__ planes)   // 8 planes of E*E shorts: h0,l0,h1,l1,...
{
  int which = blockIdx.y;
  const float* src = which == 0 ? w0 : which == 1 ? w1 : which == 2 ? w2 : w3;
  short* hi = planes + (size_t)(2 * which) * (E_ * E_);
  short* lo = planes + (size_t)(2 * which + 1) * (E_ * E_);
  int i = blockIdx.x * 256 + threadIdx.x;
  if (i >= E_ * E_ / 4) return;
  float4v t = ((const float4v*)src)[i];
  short4v h4, l4; short hh, ll;
  split2(t.x, hh, ll); h4.x = hh; l4.x = ll;
  split2(t.y, hh, ll); h4.y = hh; l4.y = ll;
  split2(t.z, hh, ll); h4.z = hh; l4.z = ll;
  split2(t.w, hh, ll); h4.w = hh; l4.w = ll;
  ((short4v*)hi)[i] = h4;
  ((short4v*)lo)[i] = l4;
}

__global__ __launch_bounds__(256) void inv_kernel(const float* __restrict__ sums,
    float* __restrict__ inv)
{
  int i = blockIdx.x * 256 + threadIdx.x;
  if (i < B_ * E_) inv[i] = 1.0f / sums[i];
}

// xnorm = attn[b,n,e] * inv[b,e] -> bf16 hi/lo planes
__global__ __launch_bounds__(256) void prep_out(const float* __restrict__ attn,
    const float* __restrict__ inv, short* __restrict__ xnh, short* __restrict__ xnl)
{
  size_t e4 = ((size_t)blockIdx.x * 256 + threadIdx.x) * 4;
  int e = (int)(e4 % E_);
  int b = (int)(e4 / ((size_t)E_ * N_));
  float4v a = *(const float4v*)(attn + e4);
  float4v iv = *(const float4v*)(inv + (size_t)b * E_ + e);
  a *= iv;
  short4v h4, l4; short hh, ll;
  split2(a.x, hh, ll); h4.x = hh; l4.x = ll;
  split2(a.y, hh, ll); h4.y = hh; l4.y = ll;
  split2(a.z, hh, ll); h4.z = hh; l4.z = ll;
  split2(a.w, hh, ll); h4.w = hh; l4.w = ll;
  *(short4v*)&xnh[e4] = h4;
  *(short4v*)&xnl[e4] = l4;
}

// C[m][n] = (sum_k A[m][k]*W[n][k] + bias[n]) * oscale, 3-product split precision.
// XCD-aware block swizzle (768 = 8*96): each XCD owns 16 consecutive m-tiles
// x all 6 n-tiles -> blocks sharing an A-tile co-resident on one L2.
template<bool OUT_PAIR>
__global__ __launch_bounds__(256) void gemm_dma(
    const short* __restrict__ Ah, const short* __restrict__ Al,
    const short* __restrict__ Wh, const short* __restrict__ Wl,
    const float* __restrict__ bias, void* __restrict__ OutH, short* __restrict__ OutL,
    float oscale)
{
  __shared__ short Ash[4096], Asl[4096], Wsh[4096], Wsl[4096];  // 128 rows x 32 k each
  const int tid = threadIdx.x;
  const int flat = blockIdx.x + blockIdx.y * 6;       // grid fixed at (6,128)
  const int nid = (flat & 7) * 96 + (flat >> 3);      // bijective: 768 = 8*96
  const int m0 = (nid / 6) * 128;
  const int n0 = (nid % 6) * 128;
  const int w = tid >> 6, lane = tid & 63, quad = lane >> 4, l16 = lane & 15;
  const int wr = w >> 1, wc = w & 1;
  const int cq = (l16 >> 1) & 3;
  const int dmarow = lane >> 2;                         // + c*16
  const int dmacc = (((lane & 3) ^ ((lane >> 3) & 3))) * 8;

  float4v acc[4][4];
#pragma unroll
  for (int a = 0; a < 4; ++a)
#pragma unroll
    for (int c = 0; c < 4; ++c) acc[a][c] = (float4v)0.0f;

  for (int kt = 0; kt < 24; ++kt) {
    const int k0 = kt * 32;
#pragma unroll
    for (int i = 0; i < 2; ++i) {
      int c = w * 2 + i;
      int ldso = c * 512 + lane * 8;                    // shorts
      size_t ga = (size_t)(m0 + c * 16 + dmarow) * E_ + k0 + dmacc;
      size_t gw = (size_t)(n0 + c * 16 + dmarow) * E_ + k0 + dmacc;
      GLOAD_LDS16(Ah + ga, &Ash[ldso]);
      GLOAD_LDS16(Al + ga, &Asl[ldso]);
      GLOAD_LDS16(Wh + gw, &Wsh[ldso]);
      GLOAD_LDS16(Wl + gw, &Wsl[ldso]);
    }
    __syncthreads();

    short8 afh[4], afl[4], bfh[4], bfl[4];
#pragma unroll
    for (int rt = 0; rt < 4; ++rt) {
      int ao = (wr * 64 + rt * 16 + l16) * 32 + (quad ^ cq) * 8;
      afh[rt] = *(const short8*)&Ash[ao];
      afl[rt] = *(const short8*)&Asl[ao];
      int wo = (wc * 64 + rt * 16 + l16) * 32 + (quad ^ cq) * 8;
      bfh[rt] = *(const short8*)&Wsh[wo];
      bfl[rt] = *(const short8*)&Wsl[wo];
    }
#pragma unroll
    for (int rt = 0; rt < 4; ++rt)
#pragma unroll
      for (int ct = 0; ct < 4; ++ct) {
        float4v a = acc[rt][ct];
        a = MFMA(afh[rt], bfh[ct], a);
        a = MFMA(afh[rt], bfl[ct], a);
        a = MFMA(afl[rt], bfh[ct], a);
        acc[rt][ct] = a;
      }
    __syncthreads();
  }

#pragma unroll
  for (int ct = 0; ct < 4; ++ct) {
    int n = n0 + wc * 64 + ct * 16 + l16;
    float bv = bias[n];
#pragma unroll
    for (int rt = 0; rt < 4; ++rt) {
#pragma unroll
      for (int i = 0; i < 4; ++i) {
        int m = m0 + wr * 64 + rt * 16 + quad * 4 + i;
        float v = (acc[rt][ct][i] + bv) * oscale;
        if constexpr (OUT_PAIR) {
          short hh, ll; split2(v, hh, ll);
          ((short*)OutH)[(size_t)m * E_ + n] = hh;
          OutL[(size_t)m * E_ + n] = ll;
        } else {
          ((float*)OutH)[(size_t)m * E_ + n] = v;
        }
      }
    }
  }
}

// cumulative jj-extent offset per head: g=h>>2, ext=8192>>g
__device__ __host__ inline int hoff_of(int g, int hg) {
  return g == 0 ? hg * 8192 : (g == 1 ? 32768 + hg * 4096 : 49152 + hg * 2048);
}

// V [b][n][h][d] hi/lo -> gathered transposed Vg [b][h][d][jj]
__global__ __launch_bounds__(256) void transpose_v(const short* __restrict__ vh,
    const short* __restrict__ vl, short* __restrict__ vgh, short* __restrict__ vgl)
{
  __shared__ short Lh[64 * 68], Ll[64 * 68];
  int bid = blockIdx.x;
  int b = 0;
  if (bid >= 896) { b = 1; bid -= 896; }
  int g, hg, tile;
  if (bid < 512)      { g = 0; hg = bid >> 7; tile = bid & 127; }
  else if (bid < 768) { g = 1; hg = (bid - 512) >> 6; tile = (bid - 512) & 63; }
  else                { g = 2; hg = (bid - 768) >> 5; tile = (bid - 768) & 31; }
  const int h = g * 4 + hg, r = 1 << g, off = g;
  const int ext = 8192 >> g;
  const int jj0 = tile * 64, seg = jj0 >> 11, j0 = jj0 & 2047;
  const int n0 = seg * (2048 << g) + off + j0 * r;
  const int tid = threadIdx.x;

#pragma unroll
  for (int p = 0; p < 2; ++p) {
    int c = tid + p * 256;
    int jr = c >> 3, c8 = (c & 7) * 8;
    size_t gsrc = ((size_t)(b * N_ + n0 + jr * r) * H_ + h) * D_ + c8;
    *(short8*)&Lh[jr * 68 + c8] = *(const short8*)(vh + gsrc);
    *(short8*)&Ll[jr * 68 + c8] = *(const short8*)(vl + gsrc);
  }
  __syncthreads();
  size_t basebh = ((size_t)b * 57344 + hoff_of(g, hg)) * 64;
#pragma unroll
  for (int p = 0; p < 2; ++p) {
    int c = tid + p * 256;
    int dd = c >> 3, jc = (c & 7) * 8;
    short8 oh, ol;
#pragma unroll
    for (int u = 0; u < 8; ++u) {
      oh[u] = Lh[(jc + u) * 68 + dd];
      ol[u] = Ll[(jc + u) * 68 + dd];
    }
    size_t gdst = basebh + (size_t)dd * ext + jj0 + jc;
    *(short8*)(vgh + gdst) = oh;
    *(short8*)(vgl + gdst) = ol;
  }
}

// Flash attention, S^T = K*Q^T / O^T = V^T*P^T, split precision.
// v7: QBLK=64 occupancy win (v6, grid 1792) WITHOUT the register blowup:
// K lives in LDS (shared by the 4 waves, staged once per block), conflict-free
// XOR layout: row stride 128B (rows bank-aligned), 16B chunk c at phys
// c^(row&7). Staging writes are an intra-row permutation (conflict-free);
// QK b128 reads span all 8 chunk positions x2 = minimum 2 passes, 0 conflict.
// V path identical to v6 (PMC-verified 0 conflicts). PV via K=16 MFMAs from
// registers. launch_bounds(256,4): cap 128 VGPR -> no spill (v6 tripwire).
__global__ __launch_bounds__(256, 4) void attn_kernel(
    const short* __restrict__ qh, const short* __restrict__ ql,
    const short* __restrict__ kh, const short* __restrict__ kl,
    const short* __restrict__ vgh, const short* __restrict__ vgl,
    float* __restrict__ attn_out, float* __restrict__ sums)
{
  __shared__ __align__(16) short Ksh[2][32 * 64], Ksl[2][32 * 64];
  __shared__ __align__(16) short Vth[2][64 * 32], Vtl[2][64 * 32];

  // XCD swizzle: 1792 = 8*224; contiguous logical ids (sharing K/V) per XCD
  int bid = (blockIdx.x & 7) * 224 + (blockIdx.x >> 3);
  int g, t;
  if (bid < 1024)      { g = 0; t = bid; }
  else if (bid < 1536) { g = 1; t = bid - 1024; }
  else                 { g = 2; t = bid - 1536; }
  const int qtile = t & 31; t >>= 5;
  const int hg = t & 3; t >>= 2;
  const int nseg = 4 >> g;
  const int seg = t & (nseg - 1);
  const int b = t / nseg;
  const int r = 1 << g;
  const int off = g;
  const int h = g * 4 + hg;
  const int segbase = seg * (2048 << g);
  const int ext = 8192 >> g;

  const int tid = threadIdx.x;
  const int w = tid >> 6, lane = tid & 63, quad = lane >> 4, l16 = lane & 15;

  const size_t vbase = ((size_t)b * 57344 + hoff_of(g, hg)) * 64 + (size_t)seg * 2048;

  // zero-fill uncovered attn slots for this block's q-range (64 rows)
  if (g > 0) {
#pragma unroll
    for (int res0 = 1; res0 < 4; ++res0) {
      if (res0 >= r) break;
      int res = (off + res0) & (r - 1);
      for (int c = 0; c < 4; ++c) {
        int idx = tid + c * 256;
        int jl = idx >> 4, d0 = (idx & 15) * 4;
        int pos = segbase + res + (qtile * 64 + jl) * r;
        *(float4v*)(attn_out + ((size_t)(b * N_ + pos) * H_ + h) * D_ + d0) = (float4v)0.f;
      }
    }
  }

  // Q B-frags (n = l16 = q, k = quad*8+j [+32*ks]); Q pre-scaled by 0.125*log2e
  short8 qfh[2], qfl[2];
  {
    int j = qtile * 64 + w * 16 + l16;
    int pos = segbase + off + j * r;
    size_t base = ((size_t)(b * N_ + pos) * H_ + h) * D_;
#pragma unroll
    for (int ks = 0; ks < 2; ++ks) {
      qfh[ks] = *(const short8*)(qh + base + ks * 32 + quad * 8);
      qfl[ks] = *(const short8*)(ql + base + ks * 32 + quad * 8);
    }
  }

  // K staging geometry: 32 rows x 64 cols, row stride 64 shorts (128B).
  // Phys 16B chunk = logical chunk ^ (row & 7); global read is linear.
  const int krow = tid >> 3;                 // 0..31
  const int kch  = tid & 7;                  // logical 16B chunk
  const int kldso = krow * 64 + (kch ^ (krow & 7)) * 8;   // shorts
  size_t gbK = ((size_t)(b * N_ + segbase + off + krow * r) * H_ + h) * D_ + kch * 8;
  const size_t stepK = (size_t)32 * r * (H_ * D_);
  // K read-side chunk XOR
  const int kxor = l16 & 7;

  // V staging geometry (v6-verified XOR swizzle, 0 conflicts)
  const int vd = tid >> 2;                  // row d 0..63
  const int vc = tid & 3;                   // phys 16B chunk 0..3
  const int vg16 = vc ^ ((vd >> 2) & 3);    // global 16B chunk (pre-swizzled)
  const bool vswap = ((vd >> 1) & 1) != 0;  // 8B half-swap
  const int vldso = vd * 32 + vc * 8;       // shorts (row stride 32 shorts = 64B)
  const int vm = l16 >> 1;                  // read-side 8B-chunk XOR mask
  size_t gbV = vbase + (size_t)vd * ext + vg16 * 8;

  short8 rvh, rvl, rkh, rkl;
#define LOADT(tt) do { \
    size_t ka_ = gbK + (size_t)(tt) * stepK; \
    size_t va_ = gbV + (size_t)(tt) * 32; \
    rkh = *(const short8*)(kh + ka_); rkl = *(const short8*)(kl + ka_); \
    rvh = *(const short8*)(vgh + va_); rvl = *(const short8*)(vgl + va_); \
  } while (0)
#define WRITET(cc) do { \
    *(short8*)&Ksh[cc][kldso] = rkh; \
    *(short8*)&Ksl[cc][kldso] = rkl; \
    short8 th_ = vswap ? __builtin_shufflevector(rvh, rvh, 4, 5, 6, 7, 0, 1, 2, 3) : rvh; \
    short8 tl_ = vswap ? __builtin_shufflevector(rvl, rvl, 4, 5, 6, 7, 0, 1, 2, 3) : rvl; \
    *(short8*)&Vth[cc][vldso] = th_; \
    *(short8*)&Vtl[cc][vldso] = tl_; \
  } while (0)

  float4v o[4];
  float mrow = -INFINITY, lrow = 0.f;
#pragma unroll
  for (int dt = 0; dt < 4; ++dt) o[dt] = (float4v)0.0f;

  // prologue: tile0 -> buf0; tile1 in regs
  LOADT(0);
  WRITET(0);
  LOADT(1);
  __syncthreads();
  int cur = 0;

  for (int kt = 0; kt < 64; ++kt) {
    WRITET(cur ^ 1);          // tile kt+1 (regs arrived last iter)
    LOADT((kt + 2) & 63);     // issue tile kt+2

    const short* Kc_h = Ksh[cur]; const short* Kc_l = Ksl[cur];

    // S^T = K*Q^T (3-product split); K from swizzled LDS, scale folded into Q
    float4v sc[2];
    __builtin_amdgcn_s_setprio(1);
#pragma unroll
    for (int kvt = 0; kvt < 2; ++kvt) {
      const int kb = (kvt * 16 + l16) * 64;
      short8 ah0 = *(const short8*)&Kc_h[kb + (quad ^ kxor) * 8];
      short8 ah1 = *(const short8*)&Kc_h[kb + ((quad + 4) ^ kxor) * 8];
      short8 al0 = *(const short8*)&Kc_l[kb + (quad ^ kxor) * 8];
      short8 al1 = *(const short8*)&Kc_l[kb + ((quad + 4) ^ kxor) * 8];
      float4v a = (float4v)0.0f;
      a = MFMA(ah0, qfh[0], a); a = MFMA(ah1, qfh[1], a);
      a = MFMA(ah0, qfl[0], a); a = MFMA(ah1, qfl[1], a);
      a = MFMA(al0, qfh[0], a); a = MFMA(al1, qfh[1], a);
      sc[kvt] = a;
    }
    __builtin_amdgcn_s_setprio(0);

    // online softmax (exp2 domain), q = l16; P stays in registers (K=16 frags)
    short4v pfh[2], pfl[2];   // [kvt]
    {
      float mx = fmaxf(fmaxf(fmaxf(sc[0][0], sc[0][1]),
                             fmaxf(sc[0][2], sc[0][3])),
                       fmaxf(fmaxf(sc[1][0], sc[1][1]),
                             fmaxf(sc[1][2], sc[1][3])));
      mx = fmaxf(mx, __shfl_xor(mx, 16, 64));
      mx = fmaxf(mx, __shfl_xor(mx, 32, 64));
      // T13 defer-max: only rescale when the max grew by more than 8
      if (__any(mx > mrow + 8.0f)) {
        float mnew = fmaxf(mrow, mx);
        float alpha = exp2f(mrow - mnew);
        mrow = mnew;
        lrow *= alpha;
#pragma unroll
        for (int dt = 0; dt < 4; ++dt) o[dt] *= alpha;
      }
      float rs = 0.f;
#pragma unroll
      for (int kvt = 0; kvt < 2; ++kvt) {
        float p0 = exp2f(sc[kvt][0] - mrow);
        float p1 = exp2f(sc[kvt][1] - mrow);
        float p2 = exp2f(sc[kvt][2] - mrow);
        float p3 = exp2f(sc[kvt][3] - mrow);
        rs += (p0 + p1) + (p2 + p3);
        union { unsigned u[2]; short4v s; } ph, pl;
        ph.u[0] = pack_trunc(p0, p1);
        ph.u[1] = pack_trunc(p2, p3);
        float l0 = p0 - __uint_as_float(__float_as_uint(p0) & 0xffff0000u);
        float l1 = p1 - __uint_as_float(__float_as_uint(p1) & 0xffff0000u);
        float l2 = p2 - __uint_as_float(__float_as_uint(p2) & 0xffff0000u);
        float l3 = p3 - __uint_as_float(__float_as_uint(p3) & 0xffff0000u);
        pl.u[0] = pack_trunc(l0, l1);
        pl.u[1] = pack_trunc(l2, l3);
        pfh[kvt] = ph.s;
        pfl[kvt] = pl.s;
      }
      lrow += rs;   // lane-partial; reduced across quads in epilogue
    }

    // O^T += V^T * P^T  (K=16 MFMAs; V via swizzled 8B reads, P from regs)
    __builtin_amdgcn_s_setprio(1);
    {
      const short* Vc_h = Vth[cur];
      const short* Vc_l = Vtl[cur];
#pragma unroll
      for (int dt = 0; dt < 4; ++dt) {
#pragma unroll
        for (int kvt = 0; kvt < 2; ++kvt) {
          const int vo = (dt * 16 + l16) * 32 + ((kvt * 4 + quad) ^ vm) * 4;
          short4v vfh = *(const short4v*)&Vc_h[vo];
          short4v vfl = *(const short4v*)&Vc_l[vo];
          float4v a = o[dt];
          a = MFMA16(vfh, pfh[kvt], a);
          a = MFMA16(vfh, pfl[kvt], a);
          a = MFMA16(vfl, pfh[kvt], a);
          o[dt] = a;
        }
      }
    }
    __builtin_amdgcn_s_setprio(0);

    __syncthreads();
    cur ^= 1;
  }
#undef LOADT
#undef WRITET

  // epilogue: finish deferred l-sum reduction, then write O and column sums
  float4v sacc[4];
#pragma unroll
  for (int dt = 0; dt < 4; ++dt) sacc[dt] = (float4v)0.0f;
  {
    lrow += __shfl_xor(lrow, 16, 64);
    lrow += __shfl_xor(lrow, 32, 64);
    float inv_l = 1.0f / lrow;
    int j = qtile * 64 + w * 16 + l16;
    int pos = segbase + off + j * r;
    float* dst = attn_out + ((size_t)(b * N_ + pos) * H_ + h) * D_;
#pragma unroll
    for (int dt = 0; dt < 4; ++dt) {
      float4v v = o[dt] * inv_l;
      *(float4v*)(dst + dt * 16 + quad * 4) = v;
      sacc[dt] += v;
    }
  }
#pragma unroll
  for (int dt = 0; dt < 4; ++dt) {
#pragma unroll
    for (int i = 0; i < 4; ++i) {
      float x = sacc[dt][i];
      x += __shfl_xor(x, 1, 64);
      x += __shfl_xor(x, 2, 64);
      x += __shfl_xor(x, 4, 64);
      x += __shfl_xor(x, 8, 64);
      if (l16 == 0)
        atomicAdd(&sums[(size_t)b * E_ + h * D_ + dt * 16 + quad * 4 + i], x);
    }
  }
}

extern "C" void kernel_launch(void* const* d_in, const int* in_sizes, int n_in,
                              void* d_out, int out_size, void* d_ws, size_t ws_size,
                              hipStream_t stream)
{
  const float* query = (const float*)d_in[0];
  const float* key_  = (const float*)d_in[1];
  const float* value = (const float*)d_in[2];
  const float* Wq = (const float*)d_in[3];
  const float* bq = (const float*)d_in[4];
  const float* Wk = (const float*)d_in[5];
  const float* bk = (const float*)d_in[6];
  const float* Wv = (const float*)d_in[7];
  const float* bv = (const float*)d_in[8];
  const float* Wo = (const float*)d_in[9];
  const float* bo = (const float*)d_in[10];

  char* ws = (char*)d_ws;
  const size_t szbf = (size_t)M_ * E_ * 2;           // 25,165,824
  const size_t szvg = (size_t)2 * 57344 * 64 * 2;    // 14,680,064
  const size_t szw  = (size_t)E_ * E_ * 2;           // 1,179,648
  short* qh_ = (short*)(ws);
  short* ql_ = (short*)(ws + 1 * szbf);
  short* kh_ = (short*)(ws + 2 * szbf);
  short* kl_ = (short*)(ws + 3 * szbf);
  short* vh_ = (short*)(ws + 4 * szbf);
  short* vl_ = (short*)(ws + 5 * szbf);
  // [6szbf, 8szbf): input-split scratch (serial q,k,v), later overlaid by vg
  short* ish = (short*)(ws + 6 * szbf);
  short* isl = (short*)(ws + 7 * szbf);
  short* vgh = (short*)(ws + 6 * szbf);
  short* vgl = (short*)(ws + 6 * szbf + szvg);
  short* wsp = (short*)(ws + 8 * szbf);              // 8 weight planes
  float* sums = (float*)(ws + 8 * szbf + 8 * szw);
  float* attn = (float*)(ws + 4 * szbf);             // overlays vh/vl (dead after transpose)
  float* inv  = (float*)qh_;                         // q dead after attn_kernel
  short* xnh = kh_;                                  // k dead after attn_kernel
  short* xnl = kl_;
  short* wqh = wsp + 0 * (szw / 2), *wql = wsp + 1 * (szw / 2);
  short* wkh = wsp + 2 * (szw / 2), *wkl = wsp + 3 * (szw / 2);
  short* wvh = wsp + 4 * (szw / 2), *wvl = wsp + 5 * (szw / 2);
  short* woh = wsp + 6 * (szw / 2), *wol = wsp + 7 * (szw / 2);

  hipMemsetAsync(sums, 0, (size_t)B_ * E_ * sizeof(float), stream);

  split_w4<<<dim3(576, 4), 256, 0, stream>>>(Wq, Wk, Wv, Wo, wsp);

  const int ac4 = M_ * E_ / 4;                       // 3,145,728 -> 12288 blocks
  dim3 gg(6, 128), gb(256);
  const float qscale = 0.18033688f;                  // 0.125 * log2(e)
  split_kernel<<<12288, 256, 0, stream>>>(query, ish, isl, ac4);
  gemm_dma<true><<<gg, gb, 0, stream>>>(ish, isl, wqh, wql, bq, qh_, ql_, qscale);
  split_kernel<<<12288, 256, 0, stream>>>(key_, ish, isl, ac4);
  gemm_dma<true><<<gg, gb, 0, stream>>>(ish, isl, wkh, wkl, bk, kh_, kl_, 1.0f);
  split_kernel<<<12288, 256, 0, stream>>>(value, ish, isl, ac4);
  gemm_dma<true><<<gg, gb, 0, stream>>>(ish, isl, wvh, wvl, bv, vh_, vl_, 1.0f);

  transpose_v<<<1792, 256, 0, stream>>>(vh_, vl_, vgh, vgl);
  attn_kernel<<<1792, 256, 0, stream>>>(qh_, ql_, kh_, kl_, vgh, vgl, attn, sums);
  inv_kernel<<<6, 256, 0, stream>>>(sums, inv);
  prep_out<<<12288, 256, 0, stream>>>(attn, inv, xnh, xnl);
  gemm_dma<false><<<gg, gb, 0, stream>>>(xnh, xnl, woh, wol, bo, d_out, nullptr, 1.0f);
}